// Round 6
// baseline (57.602 us; speedup 1.0000x reference)
//
#include <hip/hip_runtime.h>

// Problem dims (fixed by reference setup_inputs):
#define BATCH 1024
#define NSEQ  512
#define NF    64
#define HIST_BINS 1024     // ids in [0,1000)

#define HOT 16             // table rows staged in LDS (counts ~Poisson(0.5); max ~6)
#define TSTRIDE 68         // dwords per LDS table row: 64 + 4 pad (bank de-alias)

// Cold fallback (c >= HOT): compute tbl[c0][g0..g0+3] + tbl[c1][g0..g0+3] directly.
// Essentially never executed for this input; exec-masked out of the hot loop.
__device__ __noinline__ float4 cold_pair(int c0, int c1, int f4,
                                         const float* __restrict__ W1,
                                         const float* __restrict__ b1,
                                         const float* __restrict__ W2,
                                         const float* __restrict__ b2) {
    const int g0 = 4 * f4;
    float a0 = 2.0f * b2[g0 + 0], a1 = 2.0f * b2[g0 + 1];
    float a2 = 2.0f * b2[g0 + 2], a3 = 2.0f * b2[g0 + 3];
    for (int f = 0; f < NF; ++f) {
        float w = W1[f], b = b1[f];
        float hs = fmaxf((float)c0 * w + b, 0.0f) + fmaxf((float)c1 * w + b, 0.0f);
        const float* w2 = &W2[f * NF + g0];
        a0 += hs * w2[0]; a1 += hs * w2[1]; a2 += hs * w2[2]; a3 += hs * w2[3];
    }
    return make_float4(a0, a1, a2, a3);
}

// ---------------------------------------------------------------------------
// Single fused kernel. Block 2*row+which owns batch-row `row` of tensor
// `which` (0 = src-encoding, 1 = dst-encoding): 128 KB contiguous stores.
// Prologue (overlapped across resident blocks): stage ids, build both row
// histograms, AND compute the HOT table rows into LDS so the store loop's
// vmem pipe carries ONLY stores (fill-kernel profile, ~7 TB/s).
// ---------------------------------------------------------------------------
__global__ __launch_bounds__(256, 4) void fused_expand_kernel(
        const int* __restrict__ src_ids,
        const int* __restrict__ dst_ids,
        const float* __restrict__ W1,
        const float* __restrict__ b1,
        const float* __restrict__ W2,
        const float* __restrict__ b2,
        float* __restrict__ out) {
    __shared__ int     s_src[NSEQ];
    __shared__ int     s_dst[NSEQ];
    __shared__ int     hist_s[HIST_BINS];
    __shared__ int     hist_d[HIST_BINS];
    __shared__ ushort2 s_cnt[NSEQ];
    __shared__ float   s_tbl[HOT * TSTRIDE];   // padded rows, 4.4 KB

    const int t     = threadIdx.x;
    const int which = blockIdx.x & 1;
    const int row   = blockIdx.x >> 1;

    // zero histograms
#pragma unroll
    for (int i = t; i < HIST_BINS; i += 256) { hist_s[i] = 0; hist_d[i] = 0; }
    // stage both id rows
#pragma unroll
    for (int i = t; i < NSEQ; i += 256) {
        s_src[i] = src_ids[(size_t)row * NSEQ + i];
        s_dst[i] = dst_ids[(size_t)row * NSEQ + i];
    }
    // hot table rows: entry idx = t + k*256 -> (r = idx>>6, g = idx&63)
    // tbl[r][g] = b2[g] + sum_f relu(r*W1[f]+b1[f]) * W2[f][g]
#pragma unroll
    for (int k = 0; k < (HOT * NF) / 256; ++k) {   // 4 iterations
        const int idx = t + k * 256;
        const int r = idx >> 6, g = idx & 63;
        const float cf = (float)r;
        float acc = b2[g];
#pragma unroll 8
        for (int f = 0; f < NF; ++f) {
            float h = fmaxf(cf * W1[f] + b1[f], 0.0f);
            acc += h * W2[f * NF + g];
        }
        s_tbl[r * TSTRIDE + g] = acc;
    }
    __syncthreads();

    // build both histograms (guard padded id = -1)
#pragma unroll
    for (int i = t; i < NSEQ; i += 256) {
        int si = s_src[i], di = s_dst[i];
        if (si >= 0) atomicAdd(&hist_s[si], 1);
        if (di >= 0) atomicAdd(&hist_d[di], 1);
    }
    __syncthreads();

    // per-position (own, cross) counts for THIS tensor
#pragma unroll
    for (int i = t; i < NSEQ; i += 256) {
        int id = (which == 0) ? s_src[i] : s_dst[i];
        ushort2 c;
        if (id >= 0) {
            int own   = (which == 0) ? hist_s[id] : hist_d[id];
            int cross = (which == 0) ? hist_d[id] : hist_s[id];
            c.x = (unsigned short)own;
            c.y = (unsigned short)cross;
        } else {
            c.x = 0; c.y = 0;
        }
        s_cnt[i] = c;
    }
    __syncthreads();

    // store stream: out[row,n,:] = tbl[c1] + tbl[c2]; gathers from LDS only.
    float4* __restrict__ o = (float4*)(out + ((size_t)which * BATCH + row) * NSEQ * NF);
    const int NV = NSEQ * NF / 4;   // 8192 float4 per block
#pragma unroll 8
    for (int e = t; e < NV; e += 256) {
        const int n  = e >> 4;          // position (16 float4 per position)
        const int f4 = e & 15;
        const ushort2 c = s_cnt[n];
        float4 r;
        if (((int)c.x | (int)c.y) < HOT) {
            const float4 a0 = *(const float4*)&s_tbl[(int)c.x * TSTRIDE + 4 * f4];
            const float4 a1 = *(const float4*)&s_tbl[(int)c.y * TSTRIDE + 4 * f4];
            r = make_float4(a0.x + a1.x, a0.y + a1.y, a0.z + a1.z, a0.w + a1.w);
        } else {
            r = cold_pair((int)c.x, (int)c.y, f4, W1, b1, W2, b2);
        }
        o[e] = r;
    }
}

extern "C" void kernel_launch(void* const* d_in, const int* in_sizes, int n_in,
                              void* d_out, int out_size, void* d_ws, size_t ws_size,
                              hipStream_t stream) {
    const int*   src_ids = (const int*)d_in[0];
    const int*   dst_ids = (const int*)d_in[1];
    const float* W1 = (const float*)d_in[2];   // [1, F]
    const float* b1 = (const float*)d_in[3];   // [F]
    const float* W2 = (const float*)d_in[4];   // [F, F]
    const float* b2 = (const float*)d_in[5];   // [F]

    float* out = (float*)d_out;   // [2, B, N, F] flat (src encoding, then dst)

    fused_expand_kernel<<<2 * BATCH, 256, 0, stream>>>(
        src_ids, dst_ids, W1, b1, W2, b2, out);
}

// Round 7
// 50.994 us; speedup vs baseline: 1.1296x; 1.1296x over previous
//
#include <hip/hip_runtime.h>

// Problem dims (fixed by reference setup_inputs):
#define BATCH 1024
#define NSEQ  512
#define NF    64
#define TBL_N (NSEQ + 1)   // counts range 0..512
#define HIST_BINS 1024     // ids in [0,1000)

#define HOT 32             // table rows staged in LDS (counts ~Poisson(0.5), max~7)
#define TBL_BLOCKS ((TBL_N + 3) / 4)   // 129 blocks x (4 c-values * 64 threads)

// ---------------------------------------------------------------------------
// Kernel 1: full lookup table into workspace.
// tbl[c][g] = b2[g] + sum_f relu(c*W1[f]+b1[f]) * W2[f][g]
// ---------------------------------------------------------------------------
__global__ __launch_bounds__(256) void build_table_kernel(
        const float* __restrict__ W1,
        const float* __restrict__ b1,
        const float* __restrict__ W2,
        const float* __restrict__ b2,
        float* __restrict__ tbl) {
    const int c = blockIdx.x * 4 + (threadIdx.x >> 6);
    const int g = threadIdx.x & 63;
    if (c >= TBL_N) return;
    const float cf = (float)c;
    float acc = b2[g];
#pragma unroll 8
    for (int f = 0; f < NF; ++f) {
        float h = fmaxf(cf * W1[f] + b1[f], 0.0f);
        acc += h * W2[f * NF + g];
    }
    tbl[c * NF + g] = acc;
}

// ---------------------------------------------------------------------------
// Kernel 2: writer. Block 2*row+which owns batch-row `row` of tensor `which`.
// Prologue: histogram both id rows (LDS atomics), copy hot table rows
// (32 x 64 f32 = 8 KB) global->LDS, precompute per-position CLAMPED LDS byte
// offsets. Hot loop is branch-free and store-only on the vmem pipe:
//   ds_read_b32 (offset pair) + 2x ds_read_b128 (table rows) + 4 adds
//   + global_store_dwordx4.
// Positions with count >= HOT go to an LDS overflow list, fixed up after the
// main loop from the global table (never taken for this input).
// LDS: 8K hist + 8K table + 2K offsets + 1K ovf ~= 19 KB -> 8 blocks/CU.
// ---------------------------------------------------------------------------
__global__ __launch_bounds__(256) void expand_kernel(
        const int* __restrict__ src_ids,
        const int* __restrict__ dst_ids,
        const float* __restrict__ g_tbl,
        float* __restrict__ out) {
    __shared__ int            hist_s[HIST_BINS];
    __shared__ int            hist_d[HIST_BINS];
    __shared__ float          s_tbl[HOT * NF];      // 8 KB, stride 64 (no pad:
                                                    // 8-lane groups read 128B runs)
    __shared__ ushort2        s_off[NSEQ];          // clamped byte offsets (c1,c2)
    __shared__ unsigned short s_ovf[NSEQ];          // overflow positions
    __shared__ int            s_novf;

    const int t     = threadIdx.x;
    const int which = blockIdx.x & 1;    // 0 = src-encoding, 1 = dst-encoding
    const int row   = blockIdx.x >> 1;

    const int* __restrict__ own_ids = (which == 0) ? src_ids : dst_ids;

    // zero histograms + ovf counter
#pragma unroll
    for (int i = t; i < HIST_BINS; i += 256) { hist_s[i] = 0; hist_d[i] = 0; }
    if (t == 0) s_novf = 0;

    // copy hot table rows global -> LDS (2 float4 per thread)
    {
        const float4* __restrict__ g4 = (const float4*)g_tbl;
        float4* __restrict__ l4 = (float4*)s_tbl;
#pragma unroll
        for (int i = t; i < HOT * NF / 4; i += 256) l4[i] = g4[i];
    }
    __syncthreads();

    // histogram both rows (guard padded id = -1)
#pragma unroll
    for (int i = t; i < NSEQ; i += 256) {
        int si = src_ids[(size_t)row * NSEQ + i];
        int di = dst_ids[(size_t)row * NSEQ + i];
        if (si >= 0) atomicAdd(&hist_s[si], 1);
        if (di >= 0) atomicAdd(&hist_d[di], 1);
    }
    __syncthreads();

    // per-position clamped byte offsets for THIS tensor; overflow -> list
#pragma unroll
    for (int i = t; i < NSEQ; i += 256) {
        int id = own_ids[(size_t)row * NSEQ + i];
        int own = 0, cross = 0;
        if (id >= 0) {
            own   = (which == 0) ? hist_s[id] : hist_d[id];
            cross = (which == 0) ? hist_d[id] : hist_s[id];
        }
        if (own >= HOT || cross >= HOT) {
            int k = atomicAdd(&s_novf, 1);
            s_ovf[k] = (unsigned short)i;
        }
        ushort2 off;
        off.x = (unsigned short)(min(own,   HOT - 1) * (NF * 4));
        off.y = (unsigned short)(min(cross, HOT - 1) * (NF * 4));
        s_off[i] = off;
    }
    __syncthreads();

    // ---- hot store stream: vmem pipe carries ONLY stores ----
    float4* __restrict__ o = (float4*)(out + ((size_t)which * BATCH + row) * NSEQ * NF);
    const char* __restrict__ tb = (const char*)s_tbl;
    const int NV = NSEQ * NF / 4;   // 8192 float4
#pragma unroll 4
    for (int e = t; e < NV; e += 256) {
        const int n  = e >> 4;           // position (16 float4 per position)
        const int fb = (e & 15) << 4;    // byte offset within row
        const ushort2 c = s_off[n];
        const float4 a0 = *(const float4*)(tb + (int)c.x + fb);
        const float4 a1 = *(const float4*)(tb + (int)c.y + fb);
        o[e] = make_float4(a0.x + a1.x, a0.y + a1.y, a0.z + a1.z, a0.w + a1.w);
    }

    // ---- rare fixup for counts >= HOT (reads global table) ----
    __syncthreads();
    const int novf = s_novf;
    if (novf > 0) {
        const float4* __restrict__ g4 = (const float4*)g_tbl;
        for (int k = t >> 4; k < novf; k += 16) {
            const int i  = s_ovf[k];
            const int f4 = t & 15;
            const int id = own_ids[(size_t)row * NSEQ + i];
            int own = 0, cross = 0;
            if (id >= 0) {
                own   = (which == 0) ? hist_s[id] : hist_d[id];
                cross = (which == 0) ? hist_d[id] : hist_s[id];
            }
            float4 a0 = g4[own * (NF / 4) + f4];
            float4 a1 = g4[cross * (NF / 4) + f4];
            o[i * 16 + f4] = make_float4(a0.x + a1.x, a0.y + a1.y,
                                         a0.z + a1.z, a0.w + a1.w);
        }
    }
}

extern "C" void kernel_launch(void* const* d_in, const int* in_sizes, int n_in,
                              void* d_out, int out_size, void* d_ws, size_t ws_size,
                              hipStream_t stream) {
    const int*   src_ids = (const int*)d_in[0];
    const int*   dst_ids = (const int*)d_in[1];
    const float* W1 = (const float*)d_in[2];   // [1, F]
    const float* b1 = (const float*)d_in[3];   // [F]
    const float* W2 = (const float*)d_in[4];   // [F, F]
    const float* b2 = (const float*)d_in[5];   // [F]

    float* out = (float*)d_out;   // [2, B, N, F] flat (src encoding, then dst)
    float* tbl = (float*)d_ws;    // TBL_N * NF f32 = 131,328 B

    build_table_kernel<<<TBL_BLOCKS, 256, 0, stream>>>(W1, b1, W2, b2, tbl);
    expand_kernel<<<2 * BATCH, 256, 0, stream>>>(src_ids, dst_ids, tbl, out);
}